// Round 10
// baseline (180.249 us; speedup 1.0000x reference)
//
#include <hip/hip_runtime.h>

#define SEQ    8192
#define S_TILE 180            // valid output positions per tile (192 computed - 12 shrink)
#define NROW   198            // staged input rows (192 + halo 6)
#define CS     1608           // chunk stride in halves; holds 201 rows (192 + halo + pad)
#define IMS    (4*CS)         // per-image buffer stride in halves (4 chunks)
#define NTHR   256            // 4 waves; wave owns 3 n-tiles x 2 IMAGES (A-records shared)
#define NREC   33             // A-records: L0:2 (tap-packed), L1:6, L2:10, L3:14, MLP:1
#define BN_HALFOFF (NREC*512) // float area offset (in halves) inside d_ws

typedef __attribute__((ext_vector_type(8))) _Float16 half8;
typedef __attribute__((ext_vector_type(4))) float    f32x4;

__device__ __forceinline__ int uni(int v){ return __builtin_amdgcn_readfirstlane(v); }

// Unrolled (compile-time K) bias fold: sum_ci (sum_tap W[co][ci][tap]) * t_prev[ci].
template<int K>
__device__ __forceinline__ float fold_bias(const float* __restrict__ W, int co,
    const float* __restrict__ gp, const float* __restrict__ bbp,
    const float* __restrict__ rmp, const float* __restrict__ rvp)
{
    float acc = 0.f;
#pragma unroll
    for (int ci = 0; ci < 32; ++ci) {
        float sp = gp[ci] * rsqrtf(rvp[ci] + 1e-5f);
        float tp = bbp[ci] - rmp[ci]*sp;
        float wsum = 0.f;
#pragma unroll
        for (int tap = 0; tap < K; ++tap) wsum += W[(co*32 + ci)*K + tap];
        acc += wsum * tp;
    }
    return acc;
}

// ---------------- prep (identical to the hardware-verified R9 version) ----------------
// A-records in the 16x16x32 A-layout: lane l holds A[m][k=(l>>4)*8+j], q=l>>4.
//  rec 0..1  : L0 TAP-PACKED (m = rec*16+(l&15)): k = tap*4+ci (k<12), W0 raw; k>=12 -> 0.
//  rec 2..31 : L1/L2/L3 (tap,mh): m = co = mh*16+(l&15), PERMUTED ci:
//              ci(k=q*8+j) = (j>>2)*16 + q*4 + (j&3)   [matches b128 epilogue pack]
//  rec 32    : MLP: m = h = l&15, same ci perm, value = fw1[h][ci]*s3[ci].
// Float area: [4][32]{bias', oob_const} then fb1'[16].
extern "C" __global__ void prep_kernel(
    const float* w0, const float* w1, const float* w2, const float* w3,
    const float* b0, const float* g0, const float* bb0, const float* rm0, const float* rv0,
    const float* b1, const float* g1, const float* bb1, const float* rm1, const float* rv1,
    const float* b2, const float* g2, const float* bb2, const float* rm2, const float* rv2,
    const float* b3, const float* g3, const float* bb3, const float* rm3, const float* rv3,
    const float* fw1, const float* fb1, _Float16* ws)
{
    const int tid = threadIdx.x;
    const int rec = blockIdx.x;
    if (rec < NREC) {
        if (tid < 64) {
            const int lane = tid;
            const int q = lane >> 4;
            half8 h;
            if (rec < 2) {
                int co = rec*16 + (lane & 15);
#pragma unroll
                for (int j = 0; j < 8; ++j) {
                    int k = q*8 + j;
                    float wv = (k < 12) ? w0[(co*4 + (k & 3))*3 + (k >> 2)] : 0.0f;
                    h[j] = (_Float16)wv;
                }
            } else {
                const float* W; const float *gp, *rvp; int K, r2;
                if      (rec < 8)  { W = w1;  K = 3; r2 = rec - 2;  gp = g0; rvp = rv0; }
                else if (rec < 18) { W = w2;  K = 5; r2 = rec - 8;  gp = g1; rvp = rv1; }
                else if (rec < 32) { W = w3;  K = 7; r2 = rec - 18; gp = g2; rvp = rv2; }
                else               { W = fw1; K = 1; r2 = 0;        gp = g3; rvp = rv3; }
                int tap = r2 >> 1, mh = r2 & 1;
                int co  = mh*16 + (lane & 15);   // rec 32: mh=0 -> co = h
#pragma unroll
                for (int j = 0; j < 8; ++j) {
                    int ci = ((j >> 2) << 4) + q*4 + (j & 3);   // b128-pack perm
                    float wv = W[(co*32 + ci)*K + tap];
                    wv *= gp[ci] * rsqrtf(rvp[ci] + 1e-5f);     // s_prev
                    h[j] = (_Float16)wv;
                }
            }
            *(half8*)(ws + rec*512 + lane*8) = h;
        }
    } else {
        float* fa = (float*)(ws + BN_HALFOFF);
        if (tid < 128) {
            int l = tid >> 5, co = tid & 31;
            const float *g, *bb, *rm, *rv, *bi;
            if      (l == 0) { g=g0; bb=bb0; rm=rm0; rv=rv0; bi=b0; }
            else if (l == 1) { g=g1; bb=bb1; rm=rm1; rv=rv1; bi=b1; }
            else if (l == 2) { g=g2; bb=bb2; rm=rm2; rv=rv2; bi=b2; }
            else             { g=g3; bb=bb3; rm=rm3; rv=rv3; bi=b3; }
            float s = g[co] * rsqrtf(rv[co] + 1e-5f);
            float t = bb[co] - rm[co]*s;
            float bias = bi[co];
            if      (l == 1) bias += fold_bias<3>(w1, co, g0, bb0, rm0, rv0);
            else if (l == 2) bias += fold_bias<5>(w2, co, g1, bb1, rm1, rv1);
            else if (l == 3) bias += fold_bias<7>(w3, co, g2, bb2, rm2, rv2);
            fa[(l*32 + co)*2 + 0] = bias;
            fa[(l*32 + co)*2 + 1] = -t / s;    // stored value at seq-OOB output positions
        } else if (tid < 144) {
            int hh = tid - 128;
            float acc = fb1[hh];
#pragma unroll
            for (int c = 0; c < 32; ++c) {
                float s3 = g3[c] * rsqrtf(rv3[c] + 1e-5f);
                float t3 = bb3[c] - rm3[c]*s3;
                acc += fw1[hh*32 + c] * t3;
            }
            fa[256 + hh] = acc;                // fb1'
        }
    }
}

// ---------------- conv layer L1..L2, TWO images per wave ----------------
// A-records and bias table loaded ONCE, feed both images' B-fragments:
// per tap: 2 A-loads -> 6 B-reads -> 12 MFMAs (58-cyc matrix burst).
// Addressing per image identical to R9 (hardware-verified); image offset = IMS.
template<int K, int DOFF>
__device__ __forceinline__ void conv32x2(
    const _Float16* __restrict__ rec, const float2* __restrict__ bo,
    const _Float16* in, _Float16* outb, int s0, int ntb, int lane)
{
    const int q = lane >> 4, n = lane & 15;
    const _Float16* bb0 = in +       q*CS + (ntb*16 + n)*8;
    const _Float16* bb1 = in + IMS + q*CS + (ntb*16 + n)*8;

    float oobc[8];
    f32x4 acc[2][3][2];
    {
        float bias[8];
#pragma unroll
        for (int i = 0; i < 8; ++i) {
            float2 p = bo[(i >> 2)*16 + q*4 + (i & 3)];
            bias[i] = p.x; oobc[i] = p.y;
        }
#pragma unroll
        for (int im = 0; im < 2; ++im)
#pragma unroll
            for (int nt = 0; nt < 3; ++nt)
#pragma unroll
                for (int mh = 0; mh < 2; ++mh)
                    acc[im][nt][mh] = (f32x4){bias[mh*4+0], bias[mh*4+1], bias[mh*4+2], bias[mh*4+3]};
    }

    __builtin_amdgcn_s_setprio(1);
#pragma unroll
    for (int tap = 0; tap < K; ++tap) {
        half8 a0 = *(const half8*)(rec + (tap*2 + 0)*512 + lane*8);
        half8 a1 = *(const half8*)(rec + (tap*2 + 1)*512 + lane*8);
#pragma unroll
        for (int nt = 0; nt < 3; ++nt) {
            half8 bf0 = *(const half8*)(bb0 + nt*128 + tap*8);
            acc[0][nt][0] = __builtin_amdgcn_mfma_f32_16x16x32_f16(a0, bf0, acc[0][nt][0], 0, 0, 0);
            acc[0][nt][1] = __builtin_amdgcn_mfma_f32_16x16x32_f16(a1, bf0, acc[0][nt][1], 0, 0, 0);
            half8 bf1 = *(const half8*)(bb1 + nt*128 + tap*8);
            acc[1][nt][0] = __builtin_amdgcn_mfma_f32_16x16x32_f16(a0, bf1, acc[1][nt][0], 0, 0, 0);
            acc[1][nt][1] = __builtin_amdgcn_mfma_f32_16x16x32_f16(a1, bf1, acc[1][nt][1], 0, 0, 0);
        }
    }
    __builtin_amdgcn_s_setprio(0);

#pragma unroll
    for (int im = 0; im < 2; ++im)
#pragma unroll
        for (int nt = 0; nt < 3; ++nt) {
            int pos = (ntb + nt)*16 + n;
            bool oob = (unsigned)(s0 + DOFF + pos) >= SEQ;
            half8 hv;
#pragma unroll
            for (int mh = 0; mh < 2; ++mh)
#pragma unroll
                for (int r = 0; r < 4; ++r) {
                    float v = fmaxf(acc[im][nt][mh][r], 0.0f);
                    if (oob) v = oobc[mh*4 + r];
                    hv[mh*4 + r] = (_Float16)v;
                }
            *(half8*)(outb + im*IMS + q*CS + pos*8) = hv;
        }
}

// ---------------- L0 tap-packed, two images ----------------
__device__ __forceinline__ void conv32x2L0(
    const _Float16* __restrict__ rec, const float2* __restrict__ bo,
    const _Float16* in, _Float16* outb, int s0, int ntb, int lane)
{
    const int q = lane >> 4, n = lane & 15;
    const _Float16* bb0 = in +       (q & 1)*CS + (ntb*16 + n)*8;
    const _Float16* bb1 = in + IMS + (q & 1)*CS + (ntb*16 + n)*8;

    float oobc[8];
    f32x4 acc[2][3][2];
    {
        float bias[8];
#pragma unroll
        for (int i = 0; i < 8; ++i) {
            float2 p = bo[(i >> 2)*16 + q*4 + (i & 3)];
            bias[i] = p.x; oobc[i] = p.y;
        }
#pragma unroll
        for (int im = 0; im < 2; ++im)
#pragma unroll
            for (int nt = 0; nt < 3; ++nt)
#pragma unroll
                for (int mh = 0; mh < 2; ++mh)
                    acc[im][nt][mh] = (f32x4){bias[mh*4+0], bias[mh*4+1], bias[mh*4+2], bias[mh*4+3]};
    }

    half8 a0 = *(const half8*)(rec + 0*512 + lane*8);
    half8 a1 = *(const half8*)(rec + 1*512 + lane*8);
    __builtin_amdgcn_s_setprio(1);
#pragma unroll
    for (int nt = 0; nt < 3; ++nt) {
        half8 bf0 = *(const half8*)(bb0 + nt*128);
        acc[0][nt][0] = __builtin_amdgcn_mfma_f32_16x16x32_f16(a0, bf0, acc[0][nt][0], 0, 0, 0);
        acc[0][nt][1] = __builtin_amdgcn_mfma_f32_16x16x32_f16(a1, bf0, acc[0][nt][1], 0, 0, 0);
        half8 bf1 = *(const half8*)(bb1 + nt*128);
        acc[1][nt][0] = __builtin_amdgcn_mfma_f32_16x16x32_f16(a0, bf1, acc[1][nt][0], 0, 0, 0);
        acc[1][nt][1] = __builtin_amdgcn_mfma_f32_16x16x32_f16(a1, bf1, acc[1][nt][1], 0, 0, 0);
    }
    __builtin_amdgcn_s_setprio(0);

#pragma unroll
    for (int im = 0; im < 2; ++im)
#pragma unroll
        for (int nt = 0; nt < 3; ++nt) {
            int pos = (ntb + nt)*16 + n;
            bool oob = (unsigned)(s0 - 6 + pos) >= SEQ;
            half8 hv;
#pragma unroll
            for (int mh = 0; mh < 2; ++mh)
#pragma unroll
                for (int r = 0; r < 4; ++r) {
                    float v = fmaxf(acc[im][nt][mh][r], 0.0f);
                    if (oob) v = oobc[mh*4 + r];
                    hv[mh*4 + r] = (_Float16)v;
                }
            *(half8*)(outb + im*IMS + q*CS + pos*8) = hv;
        }
}

// Buffer origins: staged=s0-7 (taps in k), L0out=s0-6, L1out=s0-5, L2out=s0-3, L3=s0.
// Validity chain identical to R9 (hardware-verified): valid final rows 0..179.
extern "C" __global__ void __launch_bounds__(NTHR, 3)
dnashape_mfma(const float* __restrict__ x, const _Float16* __restrict__ ws,
              const float* __restrict__ fw2, const float* __restrict__ fb2,
              float* __restrict__ out)
{
    __shared__ _Float16 bufA[2*IMS];   // [img][4 chunks][CS]
    __shared__ _Float16 bufB[2*IMS];   // 51.4 KB total -> 3 blocks/CU
    const int tid  = threadIdx.x;
    const int tile = blockIdx.x;
    const int s0   = tile * S_TILE;
    const int b0   = blockIdx.y * 2;

    // ---- stage tap-packed, BOTH images: row r halves[k=tap*4+ci] = x[ci][s0-7+r+tap]
    {
        for (int li = tid; li < 2*NROW; li += NTHR) {
            int im = (li >= NROW);
            int r  = li - im*NROW;
            const float* xb = x + (b0 + im)*4*SEQ;
            _Float16 h[16];
#pragma unroll
            for (int tap = 0; tap < 3; ++tap) {
                int sg = s0 - 7 + r + tap;
                bool ok = (unsigned)sg < SEQ;
#pragma unroll
                for (int ci = 0; ci < 4; ++ci)
                    h[tap*4 + ci] = (_Float16)(ok ? xb[ci*SEQ + sg] : 0.f);
            }
#pragma unroll
            for (int j = 12; j < 16; ++j) h[j] = (_Float16)0.f;
            *(half8*)(&bufB[im*IMS + 0*CS + r*8]) = *(half8*)(h);
            *(half8*)(&bufB[im*IMS + 1*CS + r*8]) = *(half8*)(h + 8);
        }
        // Zero bufA halo rows 192..199, both images, all 4 chunks (64 half8 stores).
        if (tid < 64) {
            const half8 z8 = {0,0,0,0,0,0,0,0};
            *(half8*)(&bufA[(tid >> 5)*IMS + ((tid >> 3) & 3)*CS + (192 + (tid & 7))*8]) = z8;
        }
    }
    __syncthreads();

    const int lane = tid & 63;
    const int wv   = uni(tid >> 6);
    const int ntb  = wv * 3;                // wave-uniform n-tile base (3 tiles/wave)
    const float*  fa = (const float*)(ws + BN_HALFOFF);
    const float2* bo = (const float2*)fa;

    conv32x2L0      (ws,          bo,      bufB, bufA, s0, ntb, lane);
    __syncthreads();
    conv32x2<3, -5>(ws +  2*512, bo + 32, bufA, bufB, s0, ntb, lane);
    __syncthreads();
    conv32x2<5, -3>(ws +  8*512, bo + 64, bufB, bufA, s0, ntb, lane);
    __syncthreads();

    // ---- L3 fused with MLP, fully in-register, both images (R9-verified scheme).
    {
        const int q = lane >> 4, n = lane & 15;
        const _Float16* rec3 = ws + 18*512;
        const _Float16* bb0 = bufA +       q*CS + (ntb*16 + n)*8;
        const _Float16* bb1 = bufA + IMS + q*CS + (ntb*16 + n)*8;
        const float2* bo3 = bo + 96;

        f32x4 acc[2][3][2];
        {
            float bias[8];
#pragma unroll
            for (int i = 0; i < 8; ++i)
                bias[i] = bo3[(i >> 2)*16 + q*4 + (i & 3)].x;
#pragma unroll
            for (int im = 0; im < 2; ++im)
#pragma unroll
                for (int nt = 0; nt < 3; ++nt)
#pragma unroll
                    for (int mh = 0; mh < 2; ++mh)
                        acc[im][nt][mh] = (f32x4){bias[mh*4+0], bias[mh*4+1], bias[mh*4+2], bias[mh*4+3]};
        }

        __builtin_amdgcn_s_setprio(1);
#pragma unroll
        for (int tap = 0; tap < 7; ++tap) {
            half8 a0 = *(const half8*)(rec3 + (tap*2 + 0)*512 + lane*8);
            half8 a1 = *(const half8*)(rec3 + (tap*2 + 1)*512 + lane*8);
#pragma unroll
            for (int nt = 0; nt < 3; ++nt) {
                half8 bf0 = *(const half8*)(bb0 + nt*128 + tap*8);
                acc[0][nt][0] = __builtin_amdgcn_mfma_f32_16x16x32_f16(a0, bf0, acc[0][nt][0], 0, 0, 0);
                acc[0][nt][1] = __builtin_amdgcn_mfma_f32_16x16x32_f16(a1, bf0, acc[0][nt][1], 0, 0, 0);
                half8 bf1 = *(const half8*)(bb1 + nt*128 + tap*8);
                acc[1][nt][0] = __builtin_amdgcn_mfma_f32_16x16x32_f16(a0, bf1, acc[1][nt][0], 0, 0, 0);
                acc[1][nt][1] = __builtin_amdgcn_mfma_f32_16x16x32_f16(a1, bf1, acc[1][nt][1], 0, 0, 0);
            }
        }
        __builtin_amdgcn_s_setprio(0);

        half8 am = *(const half8*)(ws + 32*512 + lane*8);
        float fb1v[4], fw2v[4];
#pragma unroll
        for (int r = 0; r < 4; ++r) { fb1v[r] = fa[256 + q*4 + r]; fw2v[r] = fw2[q*4 + r]; }
        float fb2v = fb2[0];

#pragma unroll
        for (int im = 0; im < 2; ++im)
#pragma unroll
            for (int nt = 0; nt < 3; ++nt) {
                int pos = (ntb + nt)*16 + n;
                half8 hv;
#pragma unroll
                for (int mh = 0; mh < 2; ++mh)
#pragma unroll
                    for (int r = 0; r < 4; ++r)
                        hv[mh*4 + r] = (_Float16)fmaxf(acc[im][nt][mh][r], 0.0f);
                f32x4 d = {0.f, 0.f, 0.f, 0.f};
                d = __builtin_amdgcn_mfma_f32_16x16x32_f16(am, hv, d, 0, 0, 0);
                float part = 0.f;
#pragma unroll
                for (int r = 0; r < 4; ++r) part += fmaxf(d[r] + fb1v[r], 0.f)*fw2v[r];
                part += __shfl_xor(part, 16, 64);   // reduce across the 4 quads (h-blocks)
                part += __shfl_xor(part, 32, 64);
                if (lane < 16) {
                    int g = s0 + pos;
                    if (pos < S_TILE && g < SEQ) out[(b0 + im)*SEQ + g] = part + fb2v;
                }
            }
    }
}

extern "C" void kernel_launch(void* const* d_in, const int* in_sizes, int n_in,
                              void* d_out, int out_size, void* d_ws, size_t ws_size,
                              hipStream_t stream) {
    const float* p[29];
    for (int i = 0; i < 29; ++i) p[i] = (const float*)d_in[i];
    _Float16* ws = (_Float16*)d_ws;   // needs 33*1024 + 1088 = 34880 B

    prep_kernel<<<dim3(NREC + 1), 144, 0, stream>>>(
        p[1], p[7], p[13], p[19],
        p[2], p[3], p[4], p[5], p[6],
        p[8], p[9], p[10], p[11], p[12],
        p[14], p[15], p[16], p[17], p[18],
        p[20], p[21], p[22], p[23], p[24],
        p[25], p[26], ws);

    dim3 grid((SEQ + S_TILE - 1) / S_TILE, 64);   // 46 x 64, TWO images per block
    dnashape_mfma<<<grid, NTHR, 0, stream>>>(p[0], (const _Float16*)ws,
                                             p[27], p[28], (float*)d_out);
}

// Round 11
// 173.826 us; speedup vs baseline: 1.0369x; 1.0369x over previous
//
#include <hip/hip_runtime.h>

#define SEQ    8192
#define S_TILE 180            // valid output positions per tile (192 computed - 12 shrink)
#define NROW   198            // staged input rows (192 + halo 6)
#define CS     1608           // chunk stride in halves; holds 201 rows (192 + halo + pad)
#define NTHR   256            // 4 waves, ONE image per block; wave owns 3 n-tiles
#define NREC   33             // A-records: L0:2 (tap-packed), L1:6, L2:10, L3:14, MLP:1
#define BN_HALFOFF (NREC*512) // float area offset (in halves) inside d_ws

typedef __attribute__((ext_vector_type(8))) _Float16 half8;
typedef __attribute__((ext_vector_type(4))) float    f32x4;

__device__ __forceinline__ int uni(int v){ return __builtin_amdgcn_readfirstlane(v); }

// Unrolled (compile-time K) bias fold: sum_ci (sum_tap W[co][ci][tap]) * t_prev[ci].
template<int K>
__device__ __forceinline__ float fold_bias(const float* __restrict__ W, int co,
    const float* __restrict__ gp, const float* __restrict__ bbp,
    const float* __restrict__ rmp, const float* __restrict__ rvp)
{
    float acc = 0.f;
#pragma unroll
    for (int ci = 0; ci < 32; ++ci) {
        float sp = gp[ci] * rsqrtf(rvp[ci] + 1e-5f);
        float tp = bbp[ci] - rmp[ci]*sp;
        float wsum = 0.f;
#pragma unroll
        for (int tap = 0; tap < K; ++tap) wsum += W[(co*32 + ci)*K + tap];
        acc += wsum * tp;
    }
    return acc;
}

// ---------------- prep ----------------
// A-records in the 16x16x32 A-layout: lane l holds A[m][k=(l>>4)*8+j], q=l>>4.
//  rec 0..1  : L0 TAP-PACKED (m = rec*16+(l&15)): k = tap*4+ci (k<12), W0 raw; k>=12 -> 0.
//  rec 2..31 : L1/L2/L3 (tap,mh): m = co = mh*16+(l&15), PERMUTED ci:
//              ci(k=q*8+j) = (j>>2)*16 + q*4 + (j&3)   [matches b128 epilogue pack]
//              value = W[co][ci]*s_prev[ci].
//  rec 32    : MLP: m = h = l&15, same ci perm, value = fw1[h][ci]*s3[ci].
// Float area: [4][32]{bias', oob_const} then fb1'[16]. Stored activations are
// r = relu(z + bias'); seq-OOB positions store -t/s so folded math sees 0.
extern "C" __global__ void prep_kernel(
    const float* w0, const float* w1, const float* w2, const float* w3,
    const float* b0, const float* g0, const float* bb0, const float* rm0, const float* rv0,
    const float* b1, const float* g1, const float* bb1, const float* rm1, const float* rv1,
    const float* b2, const float* g2, const float* bb2, const float* rm2, const float* rv2,
    const float* b3, const float* g3, const float* bb3, const float* rm3, const float* rv3,
    const float* fw1, const float* fb1, _Float16* ws)
{
    const int tid = threadIdx.x;
    const int rec = blockIdx.x;
    if (rec < NREC) {
        if (tid < 64) {
            const int lane = tid;
            const int q = lane >> 4;
            half8 h;
            if (rec < 2) {
                // L0 tap-packed: co = rec*16 + (lane&15), k = q*8+j (R8-verified)
                int co = rec*16 + (lane & 15);
#pragma unroll
                for (int j = 0; j < 8; ++j) {
                    int k = q*8 + j;
                    float wv = (k < 12) ? w0[(co*4 + (k & 3))*3 + (k >> 2)] : 0.0f;
                    h[j] = (_Float16)wv;
                }
            } else {
                const float* W; const float *gp, *rvp; int K, r2;
                if      (rec < 8)  { W = w1;  K = 3; r2 = rec - 2;  gp = g0; rvp = rv0; }
                else if (rec < 18) { W = w2;  K = 5; r2 = rec - 8;  gp = g1; rvp = rv1; }
                else if (rec < 32) { W = w3;  K = 7; r2 = rec - 18; gp = g2; rvp = rv2; }
                else               { W = fw1; K = 1; r2 = 0;        gp = g3; rvp = rv3; }
                int tap = r2 >> 1, mh = r2 & 1;
                int co  = mh*16 + (lane & 15);   // rec 32: mh=0 -> co = h
#pragma unroll
                for (int j = 0; j < 8; ++j) {
                    int ci = ((j >> 2) << 4) + q*4 + (j & 3);   // b128-pack perm
                    float wv = W[(co*32 + ci)*K + tap];
                    wv *= gp[ci] * rsqrtf(rvp[ci] + 1e-5f);     // s_prev
                    h[j] = (_Float16)wv;
                }
            }
            *(half8*)(ws + rec*512 + lane*8) = h;
        }
    } else {
        float* fa = (float*)(ws + BN_HALFOFF);
        if (tid < 128) {
            int l = tid >> 5, co = tid & 31;
            const float *g, *bb, *rm, *rv, *bi;
            if      (l == 0) { g=g0; bb=bb0; rm=rm0; rv=rv0; bi=b0; }
            else if (l == 1) { g=g1; bb=bb1; rm=rm1; rv=rv1; bi=b1; }
            else if (l == 2) { g=g2; bb=bb2; rm=rm2; rv=rv2; bi=b2; }
            else             { g=g3; bb=bb3; rm=rm3; rv=rv3; bi=b3; }
            float s = g[co] * rsqrtf(rv[co] + 1e-5f);
            float t = bb[co] - rm[co]*s;
            float bias = bi[co];
            if      (l == 1) bias += fold_bias<3>(w1, co, g0, bb0, rm0, rv0);
            else if (l == 2) bias += fold_bias<5>(w2, co, g1, bb1, rm1, rv1);
            else if (l == 3) bias += fold_bias<7>(w3, co, g2, bb2, rm2, rv2);
            fa[(l*32 + co)*2 + 0] = bias;
            fa[(l*32 + co)*2 + 1] = -t / s;    // stored value at seq-OOB output positions
        } else if (tid < 144) {
            int hh = tid - 128;
            float acc = fb1[hh];
#pragma unroll
            for (int c = 0; c < 32; ++c) {
                float s3 = g3[c] * rsqrtf(rv3[c] + 1e-5f);
                float t3 = bb3[c] - rm3[c]*s3;
                acc += fw1[hh*32 + c] * t3;
            }
            fa[256 + hh] = acc;                // fb1'
        }
    }
}

// ---------------- conv layer L1..L2 (b128 epilogue, bias-in-acc) ----------------
// in/out: LDS f16, 4 chunks x rows x 8 halves. B-frag (lane q,n): b128 at
// q*CS + (pos)*8 -> storage half j holds ci = (j>>2)*16 + q*4 + (j&3) (perm'd
// A-records pair it). Epilogue: lane packs [mh0 r0..3 | mh1 r0..3] -> ONE b128
// at chunk q, row pos (16-lane phase groups walk ascending contiguous 16B).
template<int K, int DOFF>
__device__ __forceinline__ void conv_layer(
    const _Float16* __restrict__ rec, const float2* __restrict__ bo,
    const _Float16* in, _Float16* outb, int s0, int ntb, int lane)
{
    const int q = lane >> 4, n = lane & 15;
    const _Float16* bbase = in + q*CS + (ntb*16 + n)*8;

    float oobc[8];
    f32x4 acc[3][2];
    {
        float bias[8];
#pragma unroll
        for (int i = 0; i < 8; ++i) {
            float2 p = bo[(i >> 2)*16 + q*4 + (i & 3)];
            bias[i] = p.x; oobc[i] = p.y;
        }
#pragma unroll
        for (int nt = 0; nt < 3; ++nt)
#pragma unroll
            for (int mh = 0; mh < 2; ++mh)
                acc[nt][mh] = (f32x4){bias[mh*4+0], bias[mh*4+1], bias[mh*4+2], bias[mh*4+3]};
    }

#pragma unroll
    for (int tap = 0; tap < K; ++tap) {
        half8 a0 = *(const half8*)(rec + (tap*2 + 0)*512 + lane*8);
        half8 a1 = *(const half8*)(rec + (tap*2 + 1)*512 + lane*8);
#pragma unroll
        for (int nt = 0; nt < 3; ++nt) {
            half8 bf = *(const half8*)(bbase + nt*128 + tap*8);
            acc[nt][0] = __builtin_amdgcn_mfma_f32_16x16x32_f16(a0, bf, acc[nt][0], 0, 0, 0);
            acc[nt][1] = __builtin_amdgcn_mfma_f32_16x16x32_f16(a1, bf, acc[nt][1], 0, 0, 0);
        }
    }

#pragma unroll
    for (int nt = 0; nt < 3; ++nt) {
        int pos = (ntb + nt)*16 + n;
        bool oob = (unsigned)(s0 + DOFF + pos) >= SEQ;
        half8 hv;
#pragma unroll
        for (int mh = 0; mh < 2; ++mh)
#pragma unroll
            for (int r = 0; r < 4; ++r) {
                float v = fmaxf(acc[nt][mh][r], 0.0f);
                if (oob) v = oobc[mh*4 + r];
                hv[mh*4 + r] = (_Float16)v;
            }
        *(half8*)(outb + q*CS + pos*8) = hv;
    }
}

// ---------------- L0 tap-packed (R8-verified B path, b128 epilogue) ----------------
__device__ __forceinline__ void conv_layer0(
    const _Float16* __restrict__ rec, const float2* __restrict__ bo,
    const _Float16* in, _Float16* outb, int s0, int ntb, int lane)
{
    const int q = lane >> 4, n = lane & 15;
    const _Float16* bbase = in + (q & 1)*CS + (ntb*16 + n)*8;

    float oobc[8];
    f32x4 acc[3][2];
    {
        float bias[8];
#pragma unroll
        for (int i = 0; i < 8; ++i) {
            float2 p = bo[(i >> 2)*16 + q*4 + (i & 3)];
            bias[i] = p.x; oobc[i] = p.y;
        }
#pragma unroll
        for (int nt = 0; nt < 3; ++nt)
#pragma unroll
            for (int mh = 0; mh < 2; ++mh)
                acc[nt][mh] = (f32x4){bias[mh*4+0], bias[mh*4+1], bias[mh*4+2], bias[mh*4+3]};
    }

    half8 a0 = *(const half8*)(rec + 0*512 + lane*8);
    half8 a1 = *(const half8*)(rec + 1*512 + lane*8);
#pragma unroll
    for (int nt = 0; nt < 3; ++nt) {
        half8 bf = *(const half8*)(bbase + nt*128);
        acc[nt][0] = __builtin_amdgcn_mfma_f32_16x16x32_f16(a0, bf, acc[nt][0], 0, 0, 0);
        acc[nt][1] = __builtin_amdgcn_mfma_f32_16x16x32_f16(a1, bf, acc[nt][1], 0, 0, 0);
    }

#pragma unroll
    for (int nt = 0; nt < 3; ++nt) {
        int pos = (ntb + nt)*16 + n;
        bool oob = (unsigned)(s0 - 6 + pos) >= SEQ;
        half8 hv;
#pragma unroll
        for (int mh = 0; mh < 2; ++mh)
#pragma unroll
            for (int r = 0; r < 4; ++r) {
                float v = fmaxf(acc[nt][mh][r], 0.0f);
                if (oob) v = oobc[mh*4 + r];
                hv[mh*4 + r] = (_Float16)v;
            }
        *(half8*)(outb + q*CS + pos*8) = hv;
    }
}

// Buffer origins: staged=s0-7 (taps in k), L0out=s0-6, L1out=s0-5, L2out=s0-3, L3=s0.
// Validity chain (valid final rows 0..179): L3 reads L2out(bufA) rows <=197 (zeros at
// 192..199), L2 reads L1out(bufB) rows <=195 (rows>=192: leftover staged/finite data,
// feeds only columns past validity; MFMA columns independent), L1 reads L0out(bufA)
// rows <=193 (zeros), L0 reads staged rows <=191 (<198). Same chain as R0/R7/R8.
extern "C" __global__ void __launch_bounds__(NTHR, 6)
dnashape_mfma(const float* __restrict__ x, const _Float16* __restrict__ ws,
              const float* __restrict__ fw2, const float* __restrict__ fb2,
              float* __restrict__ out)
{
    __shared__ _Float16 bufA[4*CS];
    __shared__ _Float16 bufB[4*CS];   // 25.7 KB total -> 6 blocks/CU

    const int tid  = threadIdx.x;
    const int tile = blockIdx.x;
    const int s0   = tile * S_TILE;
    const int b    = blockIdx.y;

    // ---- stage tap-packed: row r halves[k=tap*4+ci] = x[ci][s0-7+r+tap]; k>=12 -> 0
    {
        const float* xb = x + b*4*SEQ;
        for (int li = tid; li < NROW; li += NTHR) {
            _Float16 h[16];
#pragma unroll
            for (int tap = 0; tap < 3; ++tap) {
                int sg = s0 - 7 + li + tap;
                bool ok = (unsigned)sg < SEQ;
#pragma unroll
                for (int ci = 0; ci < 4; ++ci)
                    h[tap*4 + ci] = (_Float16)(ok ? xb[ci*SEQ + sg] : 0.f);
            }
#pragma unroll
            for (int j = 12; j < 16; ++j) h[j] = (_Float16)0.f;
            *(half8*)(&bufB[0*CS + li*8]) = *(half8*)(h);
            *(half8*)(&bufB[1*CS + li*8]) = *(half8*)(h + 8);
        }
        // Zero bufA halo rows 192..199 (read beyond computed range, written by none).
        if (tid < 32) {
            const half8 z8 = {0,0,0,0,0,0,0,0};
            *(half8*)(&bufA[(tid >> 3)*CS + (192 + (tid & 7))*8]) = z8;
        }
    }
    __syncthreads();

    const int lane = tid & 63;
    const int wv   = uni(tid >> 6);
    const int ntb  = wv * 3;                // wave-uniform n-tile base (3 tiles/wave)
    const float*  fa = (const float*)(ws + BN_HALFOFF);
    const float2* bo = (const float2*)fa;

    conv_layer0      (ws,          bo,      bufB, bufA, s0, ntb, lane);
    __syncthreads();
    conv_layer<3, -5>(ws +  2*512, bo + 32, bufA, bufB, s0, ntb, lane);
    __syncthreads();
    conv_layer<5, -3>(ws +  8*512, bo + 64, bufB, bufA, s0, ntb, lane);
    __syncthreads();

    // ---- L3 fused with MLP, fully in-register (no store, no 4th barrier, no read):
    // packed epilogue half8 [mh0 r0..3 | mh1 r0..3] IS the MLP B-frag (k=q*8+j,
    // col=n) under the perm'd rec-32 A-record. No oob handling: discarded MFMA
    // columns are independent and all inputs finite.
    {
        const int q = lane >> 4, n = lane & 15;
        const _Float16* rec3 = ws + 18*512;
        const _Float16* bbase = bufA + q*CS + (ntb*16 + n)*8;
        const float2* bo3 = bo + 96;

        f32x4 acc[3][2];
        {
            float bias[8];
#pragma unroll
            for (int i = 0; i < 8; ++i)
                bias[i] = bo3[(i >> 2)*16 + q*4 + (i & 3)].x;
#pragma unroll
            for (int nt = 0; nt < 3; ++nt)
#pragma unroll
                for (int mh = 0; mh < 2; ++mh)
                    acc[nt][mh] = (f32x4){bias[mh*4+0], bias[mh*4+1], bias[mh*4+2], bias[mh*4+3]};
        }

#pragma unroll
        for (int tap = 0; tap < 7; ++tap) {
            half8 a0 = *(const half8*)(rec3 + (tap*2 + 0)*512 + lane*8);
            half8 a1 = *(const half8*)(rec3 + (tap*2 + 1)*512 + lane*8);
#pragma unroll
            for (int nt = 0; nt < 3; ++nt) {
                half8 bf = *(const half8*)(bbase + nt*128 + tap*8);
                acc[nt][0] = __builtin_amdgcn_mfma_f32_16x16x32_f16(a0, bf, acc[nt][0], 0, 0, 0);
                acc[nt][1] = __builtin_amdgcn_mfma_f32_16x16x32_f16(a1, bf, acc[nt][1], 0, 0, 0);
            }
        }

        half8 am = *(const half8*)(ws + 32*512 + lane*8);
        float fb1v[4], fw2v[4];
#pragma unroll
        for (int r = 0; r < 4; ++r) { fb1v[r] = fa[256 + q*4 + r]; fw2v[r] = fw2[q*4 + r]; }
        float fb2v = fb2[0];

#pragma unroll
        for (int nt = 0; nt < 3; ++nt) {
            int pos = (ntb + nt)*16 + n;
            half8 hv;
#pragma unroll
            for (int mh = 0; mh < 2; ++mh)
#pragma unroll
                for (int r = 0; r < 4; ++r)
                    hv[mh*4 + r] = (_Float16)fmaxf(acc[nt][mh][r], 0.0f);
            f32x4 d = {0.f, 0.f, 0.f, 0.f};
            d = __builtin_amdgcn_mfma_f32_16x16x32_f16(am, hv, d, 0, 0, 0);
            float part = 0.f;
#pragma unroll
            for (int r = 0; r < 4; ++r) part += fmaxf(d[r] + fb1v[r], 0.f)*fw2v[r];
            part += __shfl_xor(part, 16, 64);   // reduce across the 4 quads (h-blocks)
            part += __shfl_xor(part, 32, 64);
            if (lane < 16) {
                int g = s0 + pos;
                if (pos < S_TILE && g < SEQ) out[b*SEQ + g] = part + fb2v;
            }
        }
    }
}

extern "C" void kernel_launch(void* const* d_in, const int* in_sizes, int n_in,
                              void* d_out, int out_size, void* d_ws, size_t ws_size,
                              hipStream_t stream) {
    const float* p[29];
    for (int i = 0; i < 29; ++i) p[i] = (const float*)d_in[i];
    _Float16* ws = (_Float16*)d_ws;   // needs 33*1024 + 1088 = 34880 B

    prep_kernel<<<dim3(NREC + 1), 144, 0, stream>>>(
        p[1], p[7], p[13], p[19],
        p[2], p[3], p[4], p[5], p[6],
        p[8], p[9], p[10], p[11], p[12],
        p[14], p[15], p[16], p[17], p[18],
        p[20], p[21], p[22], p[23], p[24],
        p[25], p[26], ws);

    dim3 grid((SEQ + S_TILE - 1) / S_TILE, 128);   // 46 x 128, 1 image per block
    dnashape_mfma<<<grid, NTHR, 0, stream>>>(p[0], (const _Float16*)ws,
                                             p[27], p[28], (float*)d_out);
}

// Round 12
// 169.746 us; speedup vs baseline: 1.0619x; 1.0240x over previous
//
#include <hip/hip_runtime.h>

#define SEQ    8192
#define S_TILE 180            // valid output positions per tile (192 computed - 12 shrink)
#define NROW   198            // staged input rows (192 + halo 6)
#define CS     1608           // chunk stride in halves; holds 201 rows (192 + halo + pad)
#define NTHR   256            // 4 waves, ONE image per block; wave owns 3 n-tiles
#define NTILE  ((SEQ + S_TILE - 1) / S_TILE)   // 46 tiles, 0..45
#define NREC   33             // A-records: L0:2 (tap-packed), L1:6, L2:10, L3:14, MLP:1
#define BN_HALFOFF (NREC*512) // float area offset (in halves) inside d_ws

typedef __attribute__((ext_vector_type(8))) _Float16 half8;
typedef __attribute__((ext_vector_type(4))) float    f32x4;

__device__ __forceinline__ int uni(int v){ return __builtin_amdgcn_readfirstlane(v); }

// Unrolled (compile-time K) bias fold: sum_ci (sum_tap W[co][ci][tap]) * t_prev[ci].
template<int K>
__device__ __forceinline__ float fold_bias(const float* __restrict__ W, int co,
    const float* __restrict__ gp, const float* __restrict__ bbp,
    const float* __restrict__ rmp, const float* __restrict__ rvp)
{
    float acc = 0.f;
#pragma unroll
    for (int ci = 0; ci < 32; ++ci) {
        float sp = gp[ci] * rsqrtf(rvp[ci] + 1e-5f);
        float tp = bbp[ci] - rmp[ci]*sp;
        float wsum = 0.f;
#pragma unroll
        for (int tap = 0; tap < K; ++tap) wsum += W[(co*32 + ci)*K + tap];
        acc += wsum * tp;
    }
    return acc;
}

// ---------------- prep (identical to the twice-hardware-verified R9/R11 version) ----
// A-records in the 16x16x32 A-layout: lane l holds A[m][k=(l>>4)*8+j], q=l>>4.
//  rec 0..1  : L0 TAP-PACKED (m = rec*16+(l&15)): k = tap*4+ci (k<12), W0 raw; k>=12 -> 0.
//  rec 2..31 : L1/L2/L3 (tap,mh): m = co = mh*16+(l&15), PERMUTED ci:
//              ci(k=q*8+j) = (j>>2)*16 + q*4 + (j&3)   [matches b128 epilogue pack]
//  rec 32    : MLP: m = h = l&15, same ci perm, value = fw1[h][ci]*s3[ci].
// Float area: [4][32]{bias', oob_const} then fb1'[16].
extern "C" __global__ void prep_kernel(
    const float* w0, const float* w1, const float* w2, const float* w3,
    const float* b0, const float* g0, const float* bb0, const float* rm0, const float* rv0,
    const float* b1, const float* g1, const float* bb1, const float* rm1, const float* rv1,
    const float* b2, const float* g2, const float* bb2, const float* rm2, const float* rv2,
    const float* b3, const float* g3, const float* bb3, const float* rm3, const float* rv3,
    const float* fw1, const float* fb1, _Float16* ws)
{
    const int tid = threadIdx.x;
    const int rec = blockIdx.x;
    if (rec < NREC) {
        if (tid < 64) {
            const int lane = tid;
            const int q = lane >> 4;
            half8 h;
            if (rec < 2) {
                int co = rec*16 + (lane & 15);
#pragma unroll
                for (int j = 0; j < 8; ++j) {
                    int k = q*8 + j;
                    float wv = (k < 12) ? w0[(co*4 + (k & 3))*3 + (k >> 2)] : 0.0f;
                    h[j] = (_Float16)wv;
                }
            } else {
                const float* W; const float *gp, *rvp; int K, r2;
                if      (rec < 8)  { W = w1;  K = 3; r2 = rec - 2;  gp = g0; rvp = rv0; }
                else if (rec < 18) { W = w2;  K = 5; r2 = rec - 8;  gp = g1; rvp = rv1; }
                else if (rec < 32) { W = w3;  K = 7; r2 = rec - 18; gp = g2; rvp = rv2; }
                else               { W = fw1; K = 1; r2 = 0;        gp = g3; rvp = rv3; }
                int tap = r2 >> 1, mh = r2 & 1;
                int co  = mh*16 + (lane & 15);   // rec 32: mh=0 -> co = h
#pragma unroll
                for (int j = 0; j < 8; ++j) {
                    int ci = ((j >> 2) << 4) + q*4 + (j & 3);   // b128-pack perm
                    float wv = W[(co*32 + ci)*K + tap];
                    wv *= gp[ci] * rsqrtf(rvp[ci] + 1e-5f);     // s_prev
                    h[j] = (_Float16)wv;
                }
            }
            *(half8*)(ws + rec*512 + lane*8) = h;
        }
    } else {
        float* fa = (float*)(ws + BN_HALFOFF);
        if (tid < 128) {
            int l = tid >> 5, co = tid & 31;
            const float *g, *bb, *rm, *rv, *bi;
            if      (l == 0) { g=g0; bb=bb0; rm=rm0; rv=rv0; bi=b0; }
            else if (l == 1) { g=g1; bb=bb1; rm=rm1; rv=rv1; bi=b1; }
            else if (l == 2) { g=g2; bb=bb2; rm=rm2; rv=rv2; bi=b2; }
            else             { g=g3; bb=bb3; rm=rm3; rv=rv3; bi=b3; }
            float s = g[co] * rsqrtf(rv[co] + 1e-5f);
            float t = bb[co] - rm[co]*s;
            float bias = bi[co];
            if      (l == 1) bias += fold_bias<3>(w1, co, g0, bb0, rm0, rv0);
            else if (l == 2) bias += fold_bias<5>(w2, co, g1, bb1, rm1, rv1);
            else if (l == 3) bias += fold_bias<7>(w3, co, g2, bb2, rm2, rv2);
            fa[(l*32 + co)*2 + 0] = bias;
            fa[(l*32 + co)*2 + 1] = -t / s;    // stored value at seq-OOB output positions
        } else if (tid < 144) {
            int hh = tid - 128;
            float acc = fb1[hh];
#pragma unroll
            for (int c = 0; c < 32; ++c) {
                float s3 = g3[c] * rsqrtf(rv3[c] + 1e-5f);
                float t3 = bb3[c] - rm3[c]*s3;
                acc += fw1[hh*32 + c] * t3;
            }
            fa[256 + hh] = acc;                // fb1'
        }
    }
}

// ---------------- conv layer L1..L2 (b128 epilogue, bias-in-acc) ----------------
// EDGE=false (tiles 1..44): s0+DOFF+pos provably in [174,8111] -> oob machinery
// (predicate + 24 cndmask + oobc regs) compiled out. EDGE path = R9/R11 bytes.
template<int K, int DOFF, bool EDGE>
__device__ __forceinline__ void conv_layer(
    const _Float16* __restrict__ rec, const float2* __restrict__ bo,
    const _Float16* in, _Float16* outb, int s0, int ntb, int lane)
{
    const int q = lane >> 4, n = lane & 15;
    const _Float16* bbase = in + q*CS + (ntb*16 + n)*8;

    float oobc[8];
    f32x4 acc[3][2];
    {
        float bias[8];
#pragma unroll
        for (int i = 0; i < 8; ++i) {
            float2 p = bo[(i >> 2)*16 + q*4 + (i & 3)];
            bias[i] = p.x;
            if (EDGE) oobc[i] = p.y;
        }
#pragma unroll
        for (int nt = 0; nt < 3; ++nt)
#pragma unroll
            for (int mh = 0; mh < 2; ++mh)
                acc[nt][mh] = (f32x4){bias[mh*4+0], bias[mh*4+1], bias[mh*4+2], bias[mh*4+3]};
    }

#pragma unroll
    for (int tap = 0; tap < K; ++tap) {
        half8 a0 = *(const half8*)(rec + (tap*2 + 0)*512 + lane*8);
        half8 a1 = *(const half8*)(rec + (tap*2 + 1)*512 + lane*8);
#pragma unroll
        for (int nt = 0; nt < 3; ++nt) {
            half8 bf = *(const half8*)(bbase + nt*128 + tap*8);
            acc[nt][0] = __builtin_amdgcn_mfma_f32_16x16x32_f16(a0, bf, acc[nt][0], 0, 0, 0);
            acc[nt][1] = __builtin_amdgcn_mfma_f32_16x16x32_f16(a1, bf, acc[nt][1], 0, 0, 0);
        }
    }

#pragma unroll
    for (int nt = 0; nt < 3; ++nt) {
        int pos = (ntb + nt)*16 + n;
        bool oob = EDGE && ((unsigned)(s0 + DOFF + pos) >= SEQ);
        half8 hv;
#pragma unroll
        for (int mh = 0; mh < 2; ++mh)
#pragma unroll
            for (int r = 0; r < 4; ++r) {
                float v = fmaxf(acc[nt][mh][r], 0.0f);
                if (EDGE && oob) v = oobc[mh*4 + r];
                hv[mh*4 + r] = (_Float16)v;
            }
        *(half8*)(outb + q*CS + pos*8) = hv;
    }
}

// ---------------- L0 tap-packed (b128 epilogue), EDGE-specialized ----------------
template<bool EDGE>
__device__ __forceinline__ void conv_layer0(
    const _Float16* __restrict__ rec, const float2* __restrict__ bo,
    const _Float16* in, _Float16* outb, int s0, int ntb, int lane)
{
    const int q = lane >> 4, n = lane & 15;
    const _Float16* bbase = in + (q & 1)*CS + (ntb*16 + n)*8;

    float oobc[8];
    f32x4 acc[3][2];
    {
        float bias[8];
#pragma unroll
        for (int i = 0; i < 8; ++i) {
            float2 p = bo[(i >> 2)*16 + q*4 + (i & 3)];
            bias[i] = p.x;
            if (EDGE) oobc[i] = p.y;
        }
#pragma unroll
        for (int nt = 0; nt < 3; ++nt)
#pragma unroll
            for (int mh = 0; mh < 2; ++mh)
                acc[nt][mh] = (f32x4){bias[mh*4+0], bias[mh*4+1], bias[mh*4+2], bias[mh*4+3]};
    }

    half8 a0 = *(const half8*)(rec + 0*512 + lane*8);
    half8 a1 = *(const half8*)(rec + 1*512 + lane*8);
#pragma unroll
    for (int nt = 0; nt < 3; ++nt) {
        half8 bf = *(const half8*)(bbase + nt*128);
        acc[nt][0] = __builtin_amdgcn_mfma_f32_16x16x32_f16(a0, bf, acc[nt][0], 0, 0, 0);
        acc[nt][1] = __builtin_amdgcn_mfma_f32_16x16x32_f16(a1, bf, acc[nt][1], 0, 0, 0);
    }

#pragma unroll
    for (int nt = 0; nt < 3; ++nt) {
        int pos = (ntb + nt)*16 + n;
        bool oob = EDGE && ((unsigned)(s0 - 6 + pos) >= SEQ);
        half8 hv;
#pragma unroll
        for (int mh = 0; mh < 2; ++mh)
#pragma unroll
            for (int r = 0; r < 4; ++r) {
                float v = fmaxf(acc[nt][mh][r], 0.0f);
                if (EDGE && oob) v = oobc[mh*4 + r];
                hv[mh*4 + r] = (_Float16)v;
            }
        *(half8*)(outb + q*CS + pos*8) = hv;
    }
}

// ---------------- full layer chain, EDGE-templated ----------------
// Buffer origins: staged=s0-7 (taps in k), L0out=s0-6, L1out=s0-5, L2out=s0-3, L3=s0.
// Validity chain (valid final rows 0..179): as R9/R11 (twice hardware-verified).
template<bool EDGE>
__device__ __forceinline__ void layers_body(
    const _Float16* __restrict__ ws, const float* __restrict__ fw2,
    const float* __restrict__ fb2, float* __restrict__ out,
    _Float16* bufA, _Float16* bufB, int s0, int b, int ntb, int lane)
{
    const float*  fa = (const float*)(ws + BN_HALFOFF);
    const float2* bo = (const float2*)fa;

    conv_layer0<EDGE>      (ws,          bo,      bufB, bufA, s0, ntb, lane);
    __syncthreads();
    conv_layer<3, -5, EDGE>(ws +  2*512, bo + 32, bufA, bufB, s0, ntb, lane);
    __syncthreads();
    conv_layer<5, -3, EDGE>(ws +  8*512, bo + 64, bufB, bufA, s0, ntb, lane);
    __syncthreads();

    // ---- L3 fused with MLP, fully in-register (no store, no 4th barrier, no read):
    // packed epilogue half8 [mh0 r0..3 | mh1 r0..3] IS the MLP B-frag (k=q*8+j,
    // col=n) under the perm'd rec-32 A-record. No oob handling needed: discarded
    // MFMA columns are independent and all inputs finite.
    {
        const int q = lane >> 4, n = lane & 15;
        const _Float16* rec3 = ws + 18*512;
        const _Float16* bbase = bufA + q*CS + (ntb*16 + n)*8;
        const float2* bo3 = bo + 96;

        f32x4 acc[3][2];
        {
            float bias[8];
#pragma unroll
            for (int i = 0; i < 8; ++i)
                bias[i] = bo3[(i >> 2)*16 + q*4 + (i & 3)].x;
#pragma unroll
            for (int nt = 0; nt < 3; ++nt)
#pragma unroll
                for (int mh = 0; mh < 2; ++mh)
                    acc[nt][mh] = (f32x4){bias[mh*4+0], bias[mh*4+1], bias[mh*4+2], bias[mh*4+3]};
        }

#pragma unroll
        for (int tap = 0; tap < 7; ++tap) {
            half8 a0 = *(const half8*)(rec3 + (tap*2 + 0)*512 + lane*8);
            half8 a1 = *(const half8*)(rec3 + (tap*2 + 1)*512 + lane*8);
#pragma unroll
            for (int nt = 0; nt < 3; ++nt) {
                half8 bf = *(const half8*)(bbase + nt*128 + tap*8);
                acc[nt][0] = __builtin_amdgcn_mfma_f32_16x16x32_f16(a0, bf, acc[nt][0], 0, 0, 0);
                acc[nt][1] = __builtin_amdgcn_mfma_f32_16x16x32_f16(a1, bf, acc[nt][1], 0, 0, 0);
            }
        }

        half8 am = *(const half8*)(ws + 32*512 + lane*8);
        float fb1v[4], fw2v[4];
#pragma unroll
        for (int r = 0; r < 4; ++r) { fb1v[r] = fa[256 + q*4 + r]; fw2v[r] = fw2[q*4 + r]; }
        float fb2v = fb2[0];

#pragma unroll
        for (int nt = 0; nt < 3; ++nt) {
            int pos = (ntb + nt)*16 + n;
            half8 hv;
#pragma unroll
            for (int mh = 0; mh < 2; ++mh)
#pragma unroll
                for (int r = 0; r < 4; ++r)
                    hv[mh*4 + r] = (_Float16)fmaxf(acc[nt][mh][r], 0.0f);
            f32x4 d = {0.f, 0.f, 0.f, 0.f};
            d = __builtin_amdgcn_mfma_f32_16x16x32_f16(am, hv, d, 0, 0, 0);
            float part = 0.f;
#pragma unroll
            for (int r = 0; r < 4; ++r) part += fmaxf(d[r] + fb1v[r], 0.f)*fw2v[r];
            part += __shfl_xor(part, 16, 64);   // reduce across the 4 quads (h-blocks)
            part += __shfl_xor(part, 32, 64);
            if (lane < 16) {
                int g = s0 + pos;
                if (pos < S_TILE && g < SEQ) out[b*SEQ + g] = part + fb2v;
            }
        }
    }
}

extern "C" __global__ void __launch_bounds__(NTHR, 6)
dnashape_mfma(const float* __restrict__ x, const _Float16* __restrict__ ws,
              const float* __restrict__ fw2, const float* __restrict__ fb2,
              float* __restrict__ out)
{
    __shared__ _Float16 bufA[4*CS];
    __shared__ _Float16 bufB[4*CS];   // 25.7 KB total -> 6 blocks/CU

    const int tid  = threadIdx.x;
    const int tile = blockIdx.x;
    const int s0   = tile * S_TILE;
    const int b    = blockIdx.y;

    // ---- stage tap-packed: row r halves[k=tap*4+ci] = x[ci][s0-7+r+tap]; k>=12 -> 0
    {
        const float* xb = x + b*4*SEQ;
        for (int li = tid; li < NROW; li += NTHR) {
            _Float16 h[16];
#pragma unroll
            for (int tap = 0; tap < 3; ++tap) {
                int sg = s0 - 7 + li + tap;
                bool ok = (unsigned)sg < SEQ;
#pragma unroll
                for (int ci = 0; ci < 4; ++ci)
                    h[tap*4 + ci] = (_Float16)(ok ? xb[ci*SEQ + sg] : 0.f);
            }
#pragma unroll
            for (int j = 12; j < 16; ++j) h[j] = (_Float16)0.f;
            *(half8*)(&bufB[0*CS + li*8]) = *(half8*)(h);
            *(half8*)(&bufB[1*CS + li*8]) = *(half8*)(h + 8);
        }
        // Zero bufA halo rows 192..199 (read beyond computed range, written by none).
        if (tid < 32) {
            const half8 z8 = {0,0,0,0,0,0,0,0};
            *(half8*)(&bufA[(tid >> 3)*CS + (192 + (tid & 7))*8]) = z8;
        }
    }
    __syncthreads();

    const int lane = tid & 63;
    const int wv   = uni(tid >> 6);
    const int ntb  = wv * 3;                // wave-uniform n-tile base (3 tiles/wave)

    // Block-uniform branch (tile uniform across block -> barriers legal both sides).
    // Only tiles 0 and NTILE-1 can see seq-OOB positions (proof in conv_layer docs).
    if (tile == 0 || tile == NTILE - 1)
        layers_body<true >(ws, fw2, fb2, out, bufA, bufB, s0, b, ntb, lane);
    else
        layers_body<false>(ws, fw2, fb2, out, bufA, bufB, s0, b, ntb, lane);
}

extern "C" void kernel_launch(void* const* d_in, const int* in_sizes, int n_in,
                              void* d_out, int out_size, void* d_ws, size_t ws_size,
                              hipStream_t stream) {
    const float* p[29];
    for (int i = 0; i < 29; ++i) p[i] = (const float*)d_in[i];
    _Float16* ws = (_Float16*)d_ws;   // needs 33*1024 + 1088 = 34880 B

    prep_kernel<<<dim3(NREC + 1), 144, 0, stream>>>(
        p[1], p[7], p[13], p[19],
        p[2], p[3], p[4], p[5], p[6],
        p[8], p[9], p[10], p[11], p[12],
        p[14], p[15], p[16], p[17], p[18],
        p[20], p[21], p[22], p[23], p[24],
        p[25], p[26], ws);

    dim3 grid(NTILE, 128);   // 46 x 128, 1 image per block
    dnashape_mfma<<<grid, NTHR, 0, stream>>>(p[0], (const _Float16*)ws,
                                             p[27], p[28], (float*)d_out);
}

// Round 13
// 166.052 us; speedup vs baseline: 1.0855x; 1.0222x over previous
//
#include <hip/hip_runtime.h>

#define SEQ    8192
#define S_TILE 180            // valid output positions per tile (192 computed - 12 shrink)
#define NROW   198            // staged input rows (192 + halo 6)
#define CS     1608           // chunk stride in halves; holds 201 rows (192 + halo + pad)
#define NTHR   256            // 4 waves, ONE image per block; wave owns 3 n-tiles
#define NTILE  ((SEQ + S_TILE - 1) / S_TILE)   // 46 tiles, 0..45
#define NREC   33             // A-records: L0:2 (tap-packed), L1:6, L2:10, L3:14, MLP:1
#define BN_HALFOFF (NREC*512) // float area offset (in halves) inside d_ws

typedef __attribute__((ext_vector_type(8))) _Float16 half8;
typedef __attribute__((ext_vector_type(4))) float    f32x4;

__device__ __forceinline__ int uni(int v){ return __builtin_amdgcn_readfirstlane(v); }

// Unrolled (compile-time K) bias fold: sum_ci (sum_tap W[co][ci][tap]) * t_prev[ci].
template<int K>
__device__ __forceinline__ float fold_bias(const float* __restrict__ W, int co,
    const float* __restrict__ gp, const float* __restrict__ bbp,
    const float* __restrict__ rmp, const float* __restrict__ rvp)
{
    float acc = 0.f;
#pragma unroll
    for (int ci = 0; ci < 32; ++ci) {
        float sp = gp[ci] * rsqrtf(rvp[ci] + 1e-5f);
        float tp = bbp[ci] - rmp[ci]*sp;
        float wsum = 0.f;
#pragma unroll
        for (int tap = 0; tap < K; ++tap) wsum += W[(co*32 + ci)*K + tap];
        acc += wsum * tp;
    }
    return acc;
}

// ---------------- prep ----------------
// A-records in the 16x16x32 A-layout: lane l holds A[m][k=(l>>4)*8+j], q=l>>4.
//  rec 0..1  : L0 TAP-PACKED (m = rec*16+(l&15)): k = tap*4+ci (k<12), W0 raw; k>=12 -> 0.
//  rec 2..31 : L1/L2/L3 (tap,mh): m = co = mh*16+(l&15), PERMUTED ci:
//              ci(k=q*8+j) = (j>>2)*16 + q*4 + (j&3)   [matches b128 epilogue pack]
//  rec 32    : MLP: m = h = l&15, same ci perm, value = fw1[h][ci]*s3[ci].
// Float area (PRE-PERMUTED for vector loads): per (layer l, quad q) a 64B group
//   fa[l*64 + q*16 + (0..7)]  = bias'[co = mh*16 + q*4 + r]   (index mh*4+r)
//   fa[l*64 + q*16 + (8..15)] = oob_const same order
// then fb1'[16] at fa[256..271]. Stored activations are r = relu(z + bias');
// seq-OOB positions store -t/s so folded math sees 0.
extern "C" __global__ void prep_kernel(
    const float* w0, const float* w1, const float* w2, const float* w3,
    const float* b0, const float* g0, const float* bb0, const float* rm0, const float* rv0,
    const float* b1, const float* g1, const float* bb1, const float* rm1, const float* rv1,
    const float* b2, const float* g2, const float* bb2, const float* rm2, const float* rv2,
    const float* b3, const float* g3, const float* bb3, const float* rm3, const float* rv3,
    const float* fw1, const float* fb1, _Float16* ws)
{
    const int tid = threadIdx.x;
    const int rec = blockIdx.x;
    if (rec < NREC) {
        if (tid < 64) {
            const int lane = tid;
            const int q = lane >> 4;
            half8 h;
            if (rec < 2) {
                int co = rec*16 + (lane & 15);
#pragma unroll
                for (int j = 0; j < 8; ++j) {
                    int k = q*8 + j;
                    float wv = (k < 12) ? w0[(co*4 + (k & 3))*3 + (k >> 2)] : 0.0f;
                    h[j] = (_Float16)wv;
                }
            } else {
                const float* W; const float *gp, *rvp; int K, r2;
                if      (rec < 8)  { W = w1;  K = 3; r2 = rec - 2;  gp = g0; rvp = rv0; }
                else if (rec < 18) { W = w2;  K = 5; r2 = rec - 8;  gp = g1; rvp = rv1; }
                else if (rec < 32) { W = w3;  K = 7; r2 = rec - 18; gp = g2; rvp = rv2; }
                else               { W = fw1; K = 1; r2 = 0;        gp = g3; rvp = rv3; }
                int tap = r2 >> 1, mh = r2 & 1;
                int co  = mh*16 + (lane & 15);   // rec 32: mh=0 -> co = h
#pragma unroll
                for (int j = 0; j < 8; ++j) {
                    int ci = ((j >> 2) << 4) + q*4 + (j & 3);   // b128-pack perm
                    float wv = W[(co*32 + ci)*K + tap];
                    wv *= gp[ci] * rsqrtf(rvp[ci] + 1e-5f);     // s_prev
                    h[j] = (_Float16)wv;
                }
            }
            *(half8*)(ws + rec*512 + lane*8) = h;
        }
    } else {
        float* fa = (float*)(ws + BN_HALFOFF);
        if (tid < 128) {
            int l = tid >> 5, co = tid & 31;
            const float *g, *bb, *rm, *rv, *bi;
            if      (l == 0) { g=g0; bb=bb0; rm=rm0; rv=rv0; bi=b0; }
            else if (l == 1) { g=g1; bb=bb1; rm=rm1; rv=rv1; bi=b1; }
            else if (l == 2) { g=g2; bb=bb2; rm=rm2; rv=rv2; bi=b2; }
            else             { g=g3; bb=bb3; rm=rm3; rv=rv3; bi=b3; }
            float s = g[co] * rsqrtf(rv[co] + 1e-5f);
            float t = bb[co] - rm[co]*s;
            float bias = bi[co];
            if      (l == 1) bias += fold_bias<3>(w1, co, g0, bb0, rm0, rv0);
            else if (l == 2) bias += fold_bias<5>(w2, co, g1, bb1, rm1, rv1);
            else if (l == 3) bias += fold_bias<7>(w3, co, g2, bb2, rm2, rv2);
            // pre-permuted: co = mh*16 + q*4 + r -> slot (l, q, mh*4+r)
            int mh = co >> 4, q = (co >> 2) & 3, r = co & 3;
            fa[l*64 + q*16 +     mh*4 + r] = bias;
            fa[l*64 + q*16 + 8 + mh*4 + r] = -t / s;   // seq-OOB stored value
        } else if (tid < 144) {
            int hh = tid - 128;
            float acc = fb1[hh];
#pragma unroll
            for (int c = 0; c < 32; ++c) {
                float s3 = g3[c] * rsqrtf(rv3[c] + 1e-5f);
                float t3 = bb3[c] - rm3[c]*s3;
                acc += fw1[hh*32 + c] * t3;
            }
            fa[256 + hh] = acc;                // fb1'
        }
    }
}

// ---------------- conv layer L1..L2 (b128 epilogue, bias-in-acc) ----------------
// EDGE=false (tiles 1..44): s0+DOFF+pos provably in [174,8111] -> oob machinery
// compiled out. bt = fa + layer*64; lane's bias/oob = 2 (+2) contiguous float4.
template<int K, int DOFF, bool EDGE>
__device__ __forceinline__ void conv_layer(
    const _Float16* __restrict__ rec, const float* __restrict__ bt,
    const _Float16* in, _Float16* outb, int s0, int ntb, int lane)
{
    const int q = lane >> 4, n = lane & 15;
    const _Float16* bbase = in + q*CS + (ntb*16 + n)*8;
    const float* bq = bt + q*16;

    f32x4 acc[3][2];
    f32x4 ov0, ov1;
    {
        f32x4 bv0 = *(const f32x4*)(bq);       // bias co = q*4 + (0..3)
        f32x4 bv1 = *(const f32x4*)(bq + 4);   // bias co = 16 + q*4 + (0..3)
        if (EDGE) { ov0 = *(const f32x4*)(bq + 8); ov1 = *(const f32x4*)(bq + 12); }
#pragma unroll
        for (int nt = 0; nt < 3; ++nt) { acc[nt][0] = bv0; acc[nt][1] = bv1; }
    }

#pragma unroll
    for (int tap = 0; tap < K; ++tap) {
        half8 a0 = *(const half8*)(rec + (tap*2 + 0)*512 + lane*8);
        half8 a1 = *(const half8*)(rec + (tap*2 + 1)*512 + lane*8);
#pragma unroll
        for (int nt = 0; nt < 3; ++nt) {
            half8 bf = *(const half8*)(bbase + nt*128 + tap*8);
            acc[nt][0] = __builtin_amdgcn_mfma_f32_16x16x32_f16(a0, bf, acc[nt][0], 0, 0, 0);
            acc[nt][1] = __builtin_amdgcn_mfma_f32_16x16x32_f16(a1, bf, acc[nt][1], 0, 0, 0);
        }
    }

#pragma unroll
    for (int nt = 0; nt < 3; ++nt) {
        int pos = (ntb + nt)*16 + n;
        bool oob = EDGE && ((unsigned)(s0 + DOFF + pos) >= SEQ);
        half8 hv;
#pragma unroll
        for (int mh = 0; mh < 2; ++mh)
#pragma unroll
            for (int r = 0; r < 4; ++r) {
                float v = fmaxf(acc[nt][mh][r], 0.0f);
                if (EDGE && oob) v = mh ? ov1[r] : ov0[r];
                hv[mh*4 + r] = (_Float16)v;
            }
        *(half8*)(outb + q*CS + pos*8) = hv;
    }
}

// ---------------- L0 tap-packed (b128 epilogue), EDGE-specialized ----------------
template<bool EDGE>
__device__ __forceinline__ void conv_layer0(
    const _Float16* __restrict__ rec, const float* __restrict__ bt,
    const _Float16* in, _Float16* outb, int s0, int ntb, int lane)
{
    const int q = lane >> 4, n = lane & 15;
    const _Float16* bbase = in + (q & 1)*CS + (ntb*16 + n)*8;
    const float* bq = bt + q*16;

    f32x4 acc[3][2];
    f32x4 ov0, ov1;
    {
        f32x4 bv0 = *(const f32x4*)(bq);
        f32x4 bv1 = *(const f32x4*)(bq + 4);
        if (EDGE) { ov0 = *(const f32x4*)(bq + 8); ov1 = *(const f32x4*)(bq + 12); }
#pragma unroll
        for (int nt = 0; nt < 3; ++nt) { acc[nt][0] = bv0; acc[nt][1] = bv1; }
    }

    half8 a0 = *(const half8*)(rec + 0*512 + lane*8);
    half8 a1 = *(const half8*)(rec + 1*512 + lane*8);
#pragma unroll
    for (int nt = 0; nt < 3; ++nt) {
        half8 bf = *(const half8*)(bbase + nt*128);
        acc[nt][0] = __builtin_amdgcn_mfma_f32_16x16x32_f16(a0, bf, acc[nt][0], 0, 0, 0);
        acc[nt][1] = __builtin_amdgcn_mfma_f32_16x16x32_f16(a1, bf, acc[nt][1], 0, 0, 0);
    }

#pragma unroll
    for (int nt = 0; nt < 3; ++nt) {
        int pos = (ntb + nt)*16 + n;
        bool oob = EDGE && ((unsigned)(s0 - 6 + pos) >= SEQ);
        half8 hv;
#pragma unroll
        for (int mh = 0; mh < 2; ++mh)
#pragma unroll
            for (int r = 0; r < 4; ++r) {
                float v = fmaxf(acc[nt][mh][r], 0.0f);
                if (EDGE && oob) v = mh ? ov1[r] : ov0[r];
                hv[mh*4 + r] = (_Float16)v;
            }
        *(half8*)(outb + q*CS + pos*8) = hv;
    }
}

// ---------------- full layer chain, EDGE-templated ----------------
// Buffer origins: staged=s0-7 (taps in k), L0out=s0-6, L1out=s0-5, L2out=s0-3, L3=s0.
// Validity chain (valid final rows 0..179): as R9/R11/R12 (thrice hardware-verified).
template<bool EDGE>
__device__ __forceinline__ void layers_body(
    const _Float16* __restrict__ ws, const float* __restrict__ fw2,
    const float* __restrict__ fb2, float* __restrict__ out,
    _Float16* bufA, _Float16* bufB, int s0, int b, int ntb, int lane)
{
    const float* fa = (const float*)(ws + BN_HALFOFF);

    conv_layer0<EDGE>      (ws,          fa,       bufB, bufA, s0, ntb, lane);
    __syncthreads();
    conv_layer<3, -5, EDGE>(ws +  2*512, fa + 64,  bufA, bufB, s0, ntb, lane);
    __syncthreads();
    conv_layer<5, -3, EDGE>(ws +  8*512, fa + 128, bufB, bufA, s0, ntb, lane);
    __syncthreads();

    // ---- L3 fused with MLP, fully in-register (no store, no 4th barrier, no read):
    // packed epilogue half8 [mh0 r0..3 | mh1 r0..3] IS the MLP B-frag (k=q*8+j,
    // col=n) under the perm'd rec-32 A-record. No oob handling needed: discarded
    // MFMA columns are independent and all inputs finite.
    {
        const int q = lane >> 4, n = lane & 15;
        const _Float16* rec3 = ws + 18*512;
        const _Float16* bbase = bufA + q*CS + (ntb*16 + n)*8;
        const float* bq3 = fa + 192 + q*16;

        // Hoist ALL loop-invariant loads (MLP record + constants) above the chain.
        half8 am = *(const half8*)(ws + 32*512 + lane*8);
        f32x4 f1v = *(const f32x4*)(fa + 256 + q*4);   // fb1' (contiguous)
        f32x4 f2v = *(const f32x4*)(fw2 + q*4);        // fw2  (contiguous)
        float fb2v = fb2[0];

        f32x4 acc[3][2];
        {
            f32x4 bv0 = *(const f32x4*)(bq3);
            f32x4 bv1 = *(const f32x4*)(bq3 + 4);
#pragma unroll
            for (int nt = 0; nt < 3; ++nt) { acc[nt][0] = bv0; acc[nt][1] = bv1; }
        }

#pragma unroll
        for (int tap = 0; tap < 7; ++tap) {
            half8 a0 = *(const half8*)(rec3 + (tap*2 + 0)*512 + lane*8);
            half8 a1 = *(const half8*)(rec3 + (tap*2 + 1)*512 + lane*8);
#pragma unroll
            for (int nt = 0; nt < 3; ++nt) {
                half8 bf = *(const half8*)(bbase + nt*128 + tap*8);
                acc[nt][0] = __builtin_amdgcn_mfma_f32_16x16x32_f16(a0, bf, acc[nt][0], 0, 0, 0);
                acc[nt][1] = __builtin_amdgcn_mfma_f32_16x16x32_f16(a1, bf, acc[nt][1], 0, 0, 0);
            }
        }

#pragma unroll
        for (int nt = 0; nt < 3; ++nt) {
            int pos = (ntb + nt)*16 + n;
            half8 hv;
#pragma unroll
            for (int mh = 0; mh < 2; ++mh)
#pragma unroll
                for (int r = 0; r < 4; ++r)
                    hv[mh*4 + r] = (_Float16)fmaxf(acc[nt][mh][r], 0.0f);
            f32x4 d = {0.f, 0.f, 0.f, 0.f};
            d = __builtin_amdgcn_mfma_f32_16x16x32_f16(am, hv, d, 0, 0, 0);
            float part = 0.f;
#pragma unroll
            for (int r = 0; r < 4; ++r) part += fmaxf(d[r] + f1v[r], 0.f)*f2v[r];
            part += __shfl_xor(part, 16, 64);   // reduce across the 4 quads (h-blocks)
            part += __shfl_xor(part, 32, 64);
            if (lane < 16) {
                int g = s0 + pos;
                if (pos < S_TILE && g < SEQ) out[b*SEQ + g] = part + fb2v;
            }
        }
    }
}

extern "C" __global__ void __launch_bounds__(NTHR, 6)
dnashape_mfma(const float* __restrict__ x, const _Float16* __restrict__ ws,
              const float* __restrict__ fw2, const float* __restrict__ fb2,
              float* __restrict__ out)
{
    __shared__ _Float16 bufA[4*CS];
    __shared__ _Float16 bufB[4*CS];   // 25.7 KB total -> 6 blocks/CU

    const int tid  = threadIdx.x;
    const int tile = blockIdx.x;
    const int s0   = tile * S_TILE;
    const int b    = blockIdx.y;

    // ---- stage tap-packed: row r halves[k=tap*4+ci] = x[ci][s0-7+r+tap]; k>=12 -> 0
    {
        const float* xb = x + b*4*SEQ;
        for (int li = tid; li < NROW; li += NTHR) {
            _Float16 h[16];
#pragma unroll
            for (int tap = 0; tap < 3; ++tap) {
                int sg = s0 - 7 + li + tap;
                bool ok = (unsigned)sg < SEQ;
#pragma unroll
                for (int ci = 0; ci < 4; ++ci)
                    h[tap*4 + ci] = (_Float16)(ok ? xb[ci*SEQ + sg] : 0.f);
            }
#pragma unroll
            for (int j = 12; j < 16; ++j) h[j] = (_Float16)0.f;
            *(half8*)(&bufB[0*CS + li*8]) = *(half8*)(h);
            *(half8*)(&bufB[1*CS + li*8]) = *(half8*)(h + 8);
        }
        // Zero bufA halo rows 192..199 (read beyond computed range, written by none).
        if (tid < 32) {
            const half8 z8 = {0,0,0,0,0,0,0,0};
            *(half8*)(&bufA[(tid >> 3)*CS + (192 + (tid & 7))*8]) = z8;
        }
    }
    __syncthreads();

    const int lane = tid & 63;
    const int wv   = uni(tid >> 6);
    const int ntb  = wv * 3;                // wave-uniform n-tile base (3 tiles/wave)

    // Block-uniform branch (tile uniform across block -> barriers legal both sides).
    // Only tiles 0 and NTILE-1 can see seq-OOB positions.
    if (tile == 0 || tile == NTILE - 1)
        layers_body<true >(ws, fw2, fb2, out, bufA, bufB, s0, b, ntb, lane);
    else
        layers_body<false>(ws, fw2, fb2, out, bufA, bufB, s0, b, ntb, lane);
}

extern "C" void kernel_launch(void* const* d_in, const int* in_sizes, int n_in,
                              void* d_out, int out_size, void* d_ws, size_t ws_size,
                              hipStream_t stream) {
    const float* p[29];
    for (int i = 0; i < 29; ++i) p[i] = (const float*)d_in[i];
    _Float16* ws = (_Float16*)d_ws;   // needs 33*1024 + 1088 = 34880 B

    prep_kernel<<<dim3(NREC + 1), 144, 0, stream>>>(
        p[1], p[7], p[13], p[19],
        p[2], p[3], p[4], p[5], p[6],
        p[8], p[9], p[10], p[11], p[12],
        p[14], p[15], p[16], p[17], p[18],
        p[20], p[21], p[22], p[23], p[24],
        p[25], p[26], ws);

    dim3 grid(NTILE, 128);   // 46 x 128, 1 image per block
    dnashape_mfma<<<grid, NTHR, 0, stream>>>(p[0], (const _Float16*)ws,
                                             p[27], p[28], (float*)d_out);
}